// Round 9
// baseline (212.528 us; speedup 1.0000x reference)
//
#include <hip/hip_runtime.h>
#include <hip/hip_bf16.h>

#define B_ 8
#define S_ 1024
#define H_ 1024
#define NH 16
#define DH 64
#define BS (B_*S_)
#define L2E 1.44269504f

typedef unsigned short u16;
typedef __attribute__((ext_vector_type(8))) short bf16x8;
typedef __attribute__((ext_vector_type(4))) float f32x4;
typedef __attribute__((ext_vector_type(16))) float f32x16;
typedef __attribute__((ext_vector_type(4))) u16 u16x4;
typedef __attribute__((ext_vector_type(2))) unsigned int u32x2;

#define MFMA(a,b,c)   __builtin_amdgcn_mfma_f32_16x16x32_bf16((a),(b),(c),0,0,0)
#define MFMA32(a,b,c) __builtin_amdgcn_mfma_f32_32x32x16_bf16((a),(b),(c),0,0,0)

__device__ __forceinline__ u16 f2bf(float f) {
  union { float f; unsigned u; } v; v.f = f;
  unsigned r = v.u + 0x7fffu + ((v.u >> 16) & 1u);
  return (u16)(r >> 16);
}

__device__ __forceinline__ unsigned packbf2(float a, float b) {
  union { __hip_bfloat162 h; unsigned u; } v;
  v.h = __float22bfloat162_rn(float2{a, b});
  return v.u;
}

__device__ __forceinline__ void gload16(const u16* g, u16* l) {
  __builtin_amdgcn_global_load_lds(
      (const __attribute__((address_space(1))) unsigned int*)g,
      (__attribute__((address_space(3))) unsigned int*)l, 16, 0, 0);
}

// ---------------- dcoef (+ fused weight f32->bf16 conversion)
__global__ __launch_bounds__(256) void dcoef_kernel(
    const float* __restrict__ qw, const float* __restrict__ kw,
    const float* __restrict__ vw, const float* __restrict__ ww,
    const float* __restrict__ uw, const float* __restrict__ styles,
    float* __restrict__ dc, u16* __restrict__ w16) {
  int bi = blockIdx.x;            // 5*1024
  int wsel = bi >> 10;
  int o = bi & 1023;
  const float* W = (wsel == 0) ? qw : (wsel == 1) ? kw : (wsel == 2) ? vw
                   : (wsel == 3) ? ww : uw;
  int soff = (wsel < 3) ? 0 : H_;
  int tid = threadIdx.x;
  float4 w4 = *(const float4*)(W + (size_t)o * H_ + tid * 4);
  u16x4 wo = { f2bf(w4.x), f2bf(w4.y), f2bf(w4.z), f2bf(w4.w) };
  *(u16x4*)(w16 + (size_t)wsel * H_ * H_ + (size_t)o * H_ + tid * 4) = wo;
  float w2x = w4.x * w4.x, w2y = w4.y * w4.y, w2z = w4.z * w4.z, w2w = w4.w * w4.w;
  float acc[8];
#pragma unroll
  for (int b = 0; b < 8; b++) {
    float4 s4 = *(const float4*)(styles + (size_t)b * 2 * H_ + soff + tid * 4);
    acc[b] = w2x * s4.x * s4.x + w2y * s4.y * s4.y + w2z * s4.z * s4.z + w2w * s4.w * s4.w;
  }
#pragma unroll
  for (int off = 1; off < 64; off <<= 1)
#pragma unroll
    for (int b = 0; b < 8; b++) acc[b] += __shfl_xor(acc[b], off);
  __shared__ float red[4][8];
  int w = tid >> 6, l = tid & 63;
  if (l == 0)
#pragma unroll
    for (int b = 0; b < 8; b++) red[w][b] = acc[b];
  __syncthreads();
  if (tid < 8) {
    int b = tid;
    float v = red[0][b] + red[1][b] + red[2][b] + red[3][b];
    float r = rsqrtf(v + 1e-8f);
    if (wsel == 2) r *= styles[(size_t)b * 2 * H_ + H_ + o];
    dc[(size_t)wsel * B_ * H_ + b * H_ + o] = r;
  }
}

// ---------------- style-scale + layernorm, bf16 out
__global__ __launch_bounds__(256) void ln_kernel(
    const float* __restrict__ x, const float* __restrict__ styles,
    u16* __restrict__ xn) {
  int row = blockIdx.x;        // 8192
  int b = row >> 10;
  int tid = threadIdx.x;
  const float4 xv = *(const float4*)(x + (size_t)row * H_ + tid * 4);
  const float4 sv = *(const float4*)(styles + (size_t)b * 2 * H_ + tid * 4);
  float v0 = xv.x * sv.x, v1 = xv.y * sv.y, v2 = xv.z * sv.z, v3 = xv.w * sv.w;
  float sum = v0 + v1 + v2 + v3;
  float sq = v0 * v0 + v1 * v1 + v2 * v2 + v3 * v3;
#pragma unroll
  for (int off = 1; off < 64; off <<= 1) {
    sum += __shfl_xor(sum, off);
    sq += __shfl_xor(sq, off);
  }
  __shared__ float rsum[4], rsq[4];
  int w = tid >> 6;
  if ((tid & 63) == 0) { rsum[w] = sum; rsq[w] = sq; }
  __syncthreads();
  sum = rsum[0] + rsum[1] + rsum[2] + rsum[3];
  sq = rsq[0] + rsq[1] + rsq[2] + rsq[3];
  float mean = sum * (1.f / H_);
  float var = sq * (1.f / H_) - mean * mean;
  float rstd = rsqrtf(var + 1e-5f);
  u16x4 o = { f2bf((v0 - mean) * rstd), f2bf((v1 - mean) * rstd),
              f2bf((v2 - mean) * rstd), f2bf((v3 - mean) * rstd) };
  *(u16x4*)(xn + (size_t)row * H_ + tid * 4) = o;
}

// ---------------- 128x128 NT GEMM core, 128 threads = 2 waves, wave-tile
// 128x64 (acc[8][4]): 24 ds_read_b128 per 64 MFMA per block-tile (vs m97's
// 32) -> MFMA pipe longer than LDS pipe. 16KB LDS, 4 blocks/CU co-resident.
// Packed [64][64] XOR-swizzled LDS (R6-verified formulas, 0 conflicts).
__device__ __forceinline__ void stage128(const u16* __restrict__ src, int K,
                                         u16* dst, int tid) {
  int ch = tid & 7;
  int rbase = tid >> 3;   // 0..15
#pragma unroll
  for (int i = 0; i < 4; i++) {
    int lrow = i * 16 + rbase;               // packed lds row 0..63
    int lch = ch ^ (lrow & 7);               // logical chunk at this slot
    int grow = lrow * 2 + (lch >> 2);        // global row 0..127
    gload16(src + (size_t)grow * K + (lch & 3) * 8, dst + lrow * 64 + ch * 8);
  }
}

__device__ __forceinline__ void gemm128_w2(
    const u16* __restrict__ A, const u16* __restrict__ B, int K,
    u16* ldsA, u16* ldsB, f32x4 acc[8][4]) {
  const int tid = threadIdx.x;
  const int l = tid & 63, w = tid >> 6;
  const int wn = w * 64;
  const int lrow = l & 15, kc = l >> 4;      // kc = 16B chunk of the k32 slice
  for (int k0 = 0; k0 < K; k0 += 32) {
    __syncthreads();
    stage128(A + k0, K, ldsA, tid);
    stage128(B + k0, K, ldsB, tid);
    __syncthreads();
    bf16x8 bfr[4];
#pragma unroll
    for (int i = 0; i < 4; i++) {
      int y = wn + i * 16 + lrow;
      int ch = (((y & 1) << 2) | kc) ^ ((y >> 1) & 7);
      bfr[i] = *(const bf16x8*)&ldsB[(y >> 1) * 64 + ch * 8];
    }
#pragma unroll
    for (int mi = 0; mi < 8; mi++) {
      int x = mi * 16 + lrow;
      int ch = (((x & 1) << 2) | kc) ^ ((x >> 1) & 7);
      bf16x8 af = *(const bf16x8*)&ldsA[(x >> 1) * 64 + ch * 8];
#pragma unroll
      for (int ni = 0; ni < 4; ni++)
        acc[mi][ni] = MFMA(af, bfr[ni], acc[mi][ni]);
    }
  }
}

// ---------------- QKV GEMM: xn[8192,1024] @ w16[0..3072][1024]^T
__global__ __launch_bounds__(128, 2) void qkv_kernel(
    const u16* __restrict__ xn, const u16* __restrict__ w16,
    const float* __restrict__ dc, u16* __restrict__ Qb, u16* __restrict__ Kb,
    u16* __restrict__ VT, u16* __restrict__ vfl) {
  __shared__ u16 ldsA[64 * 64], ldsB[64 * 64];
  int bm = blockIdx.x;   // 64
  int bn = blockIdx.y;   // 24
  f32x4 acc[8][4] = {};
  gemm128_w2(xn + (size_t)bm * 128 * H_, w16 + (size_t)bn * 128 * H_, H_,
             ldsA, ldsB, acc);
  int l = threadIdx.x & 63, w = threadIdx.x >> 6;
  int wsel = bn >> 3;
  int col0 = (bn & 7) * 128 + w * 64;
  int row0 = bm * 128;
  const float* dcw = dc + (size_t)wsel * B_ * H_;
  // fold 1/sqrt(d) and log2(e) into Q so attention can use raw exp2
  float extra = (wsel == 0) ? 0.125f * L2E : 1.0f;
#pragma unroll
  for (int mi = 0; mi < 8; mi++) {
    int row = row0 + mi * 16 + (l >> 4) * 4;
    int b = row >> 10, s_base = row & 1023;
#pragma unroll
    for (int ni = 0; ni < 4; ni++) {
      int col = col0 + ni * 16 + (l & 15);
      int hh = col >> 6, dd = col & 63;
      float dcv = dcw[b * H_ + col] * extra;
      u16 bv[4];
#pragma unroll
      for (int rr = 0; rr < 4; rr++)
        bv[rr] = f2bf(acc[mi][ni][rr] * dcv);
      if (wsel == 0) {
#pragma unroll
        for (int rr = 0; rr < 4; rr++)
          Qb[((size_t)(b * NH + hh) * S_ + s_base + rr) * DH + dd] = bv[rr];
      } else if (wsel == 1) {
#pragma unroll
        for (int rr = 0; rr < 4; rr++)
          Kb[((size_t)(b * NH + hh) * S_ + s_base + rr) * DH + dd] = bv[rr];
      } else {
        u16x4 pv = { bv[0], bv[1], bv[2], bv[3] };
        *(u16x4*)&VT[((size_t)(b * NH + hh) * DH + dd) * S_ + s_base] = pv;
#pragma unroll
        for (int rr = 0; rr < 4; rr++)
          vfl[(size_t)(row + rr) * H_ + col] = bv[rr];
      }
    }
  }
}

// ---------------- flash attention, 32x32 MFMA + in-register P (T12)
__global__ __launch_bounds__(512) void attn_kernel(
    const u16* __restrict__ Qb, const u16* __restrict__ Kb,
    const u16* __restrict__ VT, u16* __restrict__ xat) {
  __shared__ u16 ldsK[3][64 * 64];
  __shared__ u16 ldsV[3][64 * 64];
  int tid = threadIdx.x;
  int l = tid & 63, w = tid >> 6;   // 8 waves, 32 q-rows each
  int id = blockIdx.x;
  int r = id & 7, rest = id >> 3;
  int qblk = rest & 3, a = rest >> 2;
  int hl = a * 8 + r;              // XCD-locality: same head -> same XCD
  int h = hl & 15, b = hl >> 4;
  int q0 = qblk * 256 + w * 32;
  const u16* Qp = Qb + ((size_t)(b * NH + h) * S_ + q0) * DH;
  const u16* Kp = Kb + (size_t)(b * NH + h) * S_ * DH;
  const u16* Vp = VT + (size_t)(b * NH + h) * DH * S_;
  int lq = l & 31, hi = l >> 5;
  int srow = tid >> 3, schunk = tid & 7;
  int ssw = (schunk * 8) ^ ((srow & 7) << 3);
  const u16* Ksrc = Kp + (size_t)srow * DH + ssw;
  const u16* Vsrc = Vp + (size_t)srow * S_ + ssw;
  int sdst = srow * 64 + schunk * 8;
  gload16(Ksrc, &ldsK[0][sdst]);
  gload16(Vsrc, &ldsV[0][sdst]);
  gload16(Ksrc + 64 * DH, &ldsK[1][sdst]);
  gload16(Vsrc + 64,      &ldsV[1][sdst]);
  bf16x8 qf[4];
#pragma unroll
  for (int s = 0; s < 4; s++)
    qf[s] = *(const bf16x8*)(Qp + lq * 64 + s * 16 + hi * 8);
  f32x16 acc0 = {}, acc1 = {};   // OUT^T d-blocks 0..31 / 32..63
  float ls = 0.f;
  asm volatile("s_waitcnt vmcnt(2)" ::: "memory");
  __builtin_amdgcn_s_barrier();
  int cur = 0;
  for (int t = 0; t < 16; ++t) {
    if (t + 2 < 16) {
      int nb = cur + 2; if (nb >= 3) nb -= 3;
      gload16(Ksrc + (size_t)(t + 2) * 64 * DH, &ldsK[nb][sdst]);
      gload16(Vsrc + (size_t)(t + 2) * 64,      &ldsV[nb][sdst]);
    }
    const u16* Kt = &ldsK[cur][0];
    const u16* Vt = &ldsV[cur][0];
    f32x16 z0 = {}, z1 = {};
    __builtin_amdgcn_s_setprio(1);
#pragma unroll
    for (int s = 0; s < 4; s++) {
      int ch = ((s * 2 + hi) ^ (lq & 7)) * 8;
      bf16x8 kf0 = *(const bf16x8*)&Kt[lq * 64 + ch];
      bf16x8 kf1 = *(const bf16x8*)&Kt[(32 + lq) * 64 + ch];
      z0 = MFMA32(kf0, qf[s], z0);
      z1 = MFMA32(kf1, qf[s], z1);
    }
    __builtin_amdgcn_s_setprio(0);
    float rs = 0.f;
#pragma unroll
    for (int i = 0; i < 16; i++) {
      z0[i] = __builtin_exp2f(z0[i]); rs += z0[i];
      z1[i] = __builtin_exp2f(z1[i]); rs += z1[i];
    }
    rs += __shfl_xor(rs, 32);
    ls += rs;
    bf16x8 pf[4];
#pragma unroll
    for (int g = 0; g < 2; g++) {
      unsigned pa = packbf2(z0[g * 8 + 0], z0[g * 8 + 1]);
      unsigned pb = packbf2(z0[g * 8 + 2], z0[g * 8 + 3]);
      unsigned pc = packbf2(z0[g * 8 + 4], z0[g * 8 + 5]);
      unsigned pd = packbf2(z0[g * 8 + 6], z0[g * 8 + 7]);
      u32x2 sA = __builtin_amdgcn_permlane32_swap(pa, pc, false, false);
      u32x2 sB = __builtin_amdgcn_permlane32_swap(pb, pd, false, false);
      union { unsigned u[4]; bf16x8 v; } uu;
      uu.u[0] = sA[0]; uu.u[1] = sB[0]; uu.u[2] = sA[1]; uu.u[3] = sB[1];
      pf[g] = uu.v;
    }
#pragma unroll
    for (int g = 0; g < 2; g++) {
      unsigned pa = packbf2(z1[g * 8 + 0], z1[g * 8 + 1]);
      unsigned pb = packbf2(z1[g * 8 + 2], z1[g * 8 + 3]);
      unsigned pc = packbf2(z1[g * 8 + 4], z1[g * 8 + 5]);
      unsigned pd = packbf2(z1[g * 8 + 6], z1[g * 8 + 7]);
      u32x2 sA = __builtin_amdgcn_permlane32_swap(pa, pc, false, false);
      u32x2 sB = __builtin_amdgcn_permlane32_swap(pb, pd, false, false);
      union { unsigned u[4]; bf16x8 v; } uu;
      uu.u[0] = sA[0]; uu.u[1] = sB[0]; uu.u[2] = sA[1]; uu.u[3] = sB[1];
      pf[2 + g] = uu.v;
    }
    __builtin_amdgcn_s_setprio(1);
#pragma unroll
    for (int ks = 0; ks < 4; ks++) {
      int ch = ((ks * 2 + hi) ^ (lq & 7)) * 8;
      bf16x8 vf0 = *(const bf16x8*)&Vt[lq * 64 + ch];
      bf16x8 vf1 = *(const bf16x8*)&Vt[(32 + lq) * 64 + ch];
      acc0 = MFMA32(vf0, pf[ks], acc0);
      acc1 = MFMA32(vf1, pf[ks], acc1);
    }
    __builtin_amdgcn_s_setprio(0);
    if (t < 14) {
      asm volatile("s_waitcnt vmcnt(2)" ::: "memory");
    } else if (t == 14) {
      asm volatile("s_waitcnt vmcnt(0)" ::: "memory");
    }
    if (t < 15) __builtin_amdgcn_s_barrier();
    cur = (cur == 2) ? 0 : cur + 1;
  }
  float inv = 1.f / ls;
  size_t orow = ((size_t)b * S_ + q0 + lq) * H_ + h * DH;
#pragma unroll
  for (int g = 0; g < 4; g++) {
    int d0 = g * 8 + hi * 4;
    u16x4 o0 = { f2bf(acc0[g * 4 + 0] * inv), f2bf(acc0[g * 4 + 1] * inv),
                 f2bf(acc0[g * 4 + 2] * inv), f2bf(acc0[g * 4 + 3] * inv) };
    *(u16x4*)(xat + orow + d0) = o0;
    u16x4 o1 = { f2bf(acc1[g * 4 + 0] * inv), f2bf(acc1[g * 4 + 1] * inv),
                 f2bf(acc1[g * 4 + 2] * inv), f2bf(acc1[g * 4 + 3] * inv) };
    *(u16x4*)(xat + orow + 32 + d0) = o1;
  }
}

// ---------------- out GEMM: (xat@W^T)*wdc + (vfl@U^T)*udc, f32 out
__global__ __launch_bounds__(128, 2) void out_kernel(
    const u16* __restrict__ xat, const u16* __restrict__ vfl,
    const u16* __restrict__ w16, const float* __restrict__ dc,
    float* __restrict__ out) {
  __shared__ u16 ldsA[64 * 64], ldsB[64 * 64];
  int bm = blockIdx.x;   // 64
  int bn = blockIdx.y;   // 8
  f32x4 acc[8][4] = {};
  gemm128_w2(xat + (size_t)bm * 128 * H_,
             w16 + (size_t)3 * H_ * H_ + (size_t)bn * 128 * H_, H_,
             ldsA, ldsB, acc);
  int l = threadIdx.x & 63, w = threadIdx.x >> 6;
  int col0 = bn * 128 + w * 64;
  int row0 = bm * 128;
  int b = row0 >> 10;
  const float* wdc = dc + (size_t)3 * B_ * H_ + b * H_;
  const float* udc = dc + (size_t)4 * B_ * H_ + b * H_;
  float ratio[4], ud[4];
#pragma unroll
  for (int ni = 0; ni < 4; ni++) {
    int col = col0 + ni * 16 + (l & 15);
    ud[ni] = udc[col];
    ratio[ni] = wdc[col] / ud[ni];
  }
#pragma unroll
  for (int mi = 0; mi < 8; mi++)
#pragma unroll
    for (int ni = 0; ni < 4; ni++)
#pragma unroll
      for (int rr = 0; rr < 4; rr++) acc[mi][ni][rr] *= ratio[ni];
  gemm128_w2(vfl + (size_t)bm * 128 * H_,
             w16 + (size_t)4 * H_ * H_ + (size_t)bn * 128 * H_, H_,
             ldsA, ldsB, acc);
#pragma unroll
  for (int mi = 0; mi < 8; mi++) {
    int row = row0 + mi * 16 + (l >> 4) * 4;
#pragma unroll
    for (int ni = 0; ni < 4; ni++) {
      int col = col0 + ni * 16 + (l & 15);
#pragma unroll
      for (int rr = 0; rr < 4; rr++)
        out[(size_t)(row + rr) * H_ + col] = acc[mi][ni][rr] * ud[ni];
    }
  }
}

extern "C" void kernel_launch(void* const* d_in, const int* in_sizes, int n_in,
                              void* d_out, int out_size, void* d_ws, size_t ws_size,
                              hipStream_t stream) {
  const float* x = (const float*)d_in[0];
  const float* qw = (const float*)d_in[1];
  const float* kw = (const float*)d_in[2];
  const float* vw = (const float*)d_in[3];
  const float* ww = (const float*)d_in[4];
  const float* uw = (const float*)d_in[5];
  const float* styles = (const float*)d_in[6];
  float* out = (float*)d_out;

  char* ws = (char*)d_ws;
  size_t need = 163840 + (size_t)5 * H_ * H_ * 2 + (size_t)6 * BS * H_ * 2;
  if (ws_size < need) return;
  float* dc = (float*)ws;
  u16* w16 = (u16*)(ws + 163840);
  u16* xn  = w16 + (size_t)5 * H_ * H_;
  u16* Qb  = xn + (size_t)BS * H_;
  u16* Kb  = Qb + (size_t)BS * H_;
  u16* VT  = Kb + (size_t)BS * H_;
  u16* vfl = VT + (size_t)BS * H_;
  u16* xat = vfl + (size_t)BS * H_;

  dcoef_kernel<<<dim3(5 * H_), dim3(256), 0, stream>>>(qw, kw, vw, ww, uw, styles, dc, w16);
  ln_kernel<<<dim3(BS), dim3(256), 0, stream>>>(x, styles, xn);
  qkv_kernel<<<dim3(64, 24), dim3(128), 0, stream>>>(xn, w16, dc, Qb, Kb, VT, vfl);
  attn_kernel<<<dim3(512), dim3(512), 0, stream>>>(Qb, Kb, VT, xat);
  out_kernel<<<dim3(64, 8), dim3(128), 0, stream>>>(xat, vfl, w16, dc, out);
}

// Round 10
// 211.008 us; speedup vs baseline: 1.0072x; 1.0072x over previous
//
#include <hip/hip_runtime.h>
#include <hip/hip_bf16.h>

#define B_ 8
#define S_ 1024
#define H_ 1024
#define NH 16
#define DH 64
#define BS (B_*S_)
#define L2E 1.44269504f

typedef unsigned short u16;
typedef __attribute__((ext_vector_type(8))) short bf16x8;
typedef __attribute__((ext_vector_type(4))) float f32x4;
typedef __attribute__((ext_vector_type(16))) float f32x16;
typedef __attribute__((ext_vector_type(4))) u16 u16x4;
typedef __attribute__((ext_vector_type(2))) unsigned int u32x2;

#define MFMA(a,b,c)   __builtin_amdgcn_mfma_f32_16x16x32_bf16((a),(b),(c),0,0,0)
#define MFMA32(a,b,c) __builtin_amdgcn_mfma_f32_32x32x16_bf16((a),(b),(c),0,0,0)

__device__ __forceinline__ u16 f2bf(float f) {
  union { float f; unsigned u; } v; v.f = f;
  unsigned r = v.u + 0x7fffu + ((v.u >> 16) & 1u);
  return (u16)(r >> 16);
}

__device__ __forceinline__ unsigned packbf2(float a, float b) {
  union { __hip_bfloat162 h; unsigned u; } v;
  v.h = __float22bfloat162_rn(float2{a, b});
  return v.u;
}

__device__ __forceinline__ void gload16(const u16* g, u16* l) {
  __builtin_amdgcn_global_load_lds(
      (const __attribute__((address_space(1))) unsigned int*)g,
      (__attribute__((address_space(3))) unsigned int*)l, 16, 0, 0);
}

// ---------------- dcoef (+ fused weight f32->bf16 conversion)
__global__ __launch_bounds__(256) void dcoef_kernel(
    const float* __restrict__ qw, const float* __restrict__ kw,
    const float* __restrict__ vw, const float* __restrict__ ww,
    const float* __restrict__ uw, const float* __restrict__ styles,
    float* __restrict__ dc, u16* __restrict__ w16) {
  int bi = blockIdx.x;            // 5*1024
  int wsel = bi >> 10;
  int o = bi & 1023;
  const float* W = (wsel == 0) ? qw : (wsel == 1) ? kw : (wsel == 2) ? vw
                   : (wsel == 3) ? ww : uw;
  int soff = (wsel < 3) ? 0 : H_;
  int tid = threadIdx.x;
  float4 w4 = *(const float4*)(W + (size_t)o * H_ + tid * 4);
  u16x4 wo = { f2bf(w4.x), f2bf(w4.y), f2bf(w4.z), f2bf(w4.w) };
  *(u16x4*)(w16 + (size_t)wsel * H_ * H_ + (size_t)o * H_ + tid * 4) = wo;
  float w2x = w4.x * w4.x, w2y = w4.y * w4.y, w2z = w4.z * w4.z, w2w = w4.w * w4.w;
  float acc[8];
#pragma unroll
  for (int b = 0; b < 8; b++) {
    float4 s4 = *(const float4*)(styles + (size_t)b * 2 * H_ + soff + tid * 4);
    acc[b] = w2x * s4.x * s4.x + w2y * s4.y * s4.y + w2z * s4.z * s4.z + w2w * s4.w * s4.w;
  }
#pragma unroll
  for (int off = 1; off < 64; off <<= 1)
#pragma unroll
    for (int b = 0; b < 8; b++) acc[b] += __shfl_xor(acc[b], off);
  __shared__ float red[4][8];
  int w = tid >> 6, l = tid & 63;
  if (l == 0)
#pragma unroll
    for (int b = 0; b < 8; b++) red[w][b] = acc[b];
  __syncthreads();
  if (tid < 8) {
    int b = tid;
    float v = red[0][b] + red[1][b] + red[2][b] + red[3][b];
    float r = rsqrtf(v + 1e-8f);
    if (wsel == 2) r *= styles[(size_t)b * 2 * H_ + H_ + o];
    dc[(size_t)wsel * B_ * H_ + b * H_ + o] = r;
  }
}

// ---------------- style-scale + layernorm, bf16 out
__global__ __launch_bounds__(256) void ln_kernel(
    const float* __restrict__ x, const float* __restrict__ styles,
    u16* __restrict__ xn) {
  int row = blockIdx.x;        // 8192
  int b = row >> 10;
  int tid = threadIdx.x;
  const float4 xv = *(const float4*)(x + (size_t)row * H_ + tid * 4);
  const float4 sv = *(const float4*)(styles + (size_t)b * 2 * H_ + tid * 4);
  float v0 = xv.x * sv.x, v1 = xv.y * sv.y, v2 = xv.z * sv.z, v3 = xv.w * sv.w;
  float sum = v0 + v1 + v2 + v3;
  float sq = v0 * v0 + v1 * v1 + v2 * v2 + v3 * v3;
#pragma unroll
  for (int off = 1; off < 64; off <<= 1) {
    sum += __shfl_xor(sum, off);
    sq += __shfl_xor(sq, off);
  }
  __shared__ float rsum[4], rsq[4];
  int w = tid >> 6;
  if ((tid & 63) == 0) { rsum[w] = sum; rsq[w] = sq; }
  __syncthreads();
  sum = rsum[0] + rsum[1] + rsum[2] + rsum[3];
  sq = rsq[0] + rsq[1] + rsq[2] + rsq[3];
  float mean = sum * (1.f / H_);
  float var = sq * (1.f / H_) - mean * mean;
  float rstd = rsqrtf(var + 1e-5f);
  u16x4 o = { f2bf((v0 - mean) * rstd), f2bf((v1 - mean) * rstd),
              f2bf((v2 - mean) * rstd), f2bf((v3 - mean) * rstd) };
  *(u16x4*)(xn + (size_t)row * H_ + tid * 4) = o;
}

// ---------------- QKV GEMM: BM=256 x BN=128, 4 waves (2Mx2N), wave-tile
// 128x64 (12 ds_read_b128 per 32 MFMA), BK=32, 3-buffer ring (72KB LDS ->
// 2 blocks/CU), depth-2 prefetch, one vmcnt(6)+barrier per K-tile.
// Packed [64][64] XOR-swizzled LDS blocks (R6/R8-verified formulas).
__device__ __forceinline__ void stageBlk(const u16* __restrict__ src,
                                         u16* dst, int tid) {
#pragma unroll
  for (int i = 0; i < 2; i++) {
    int lr2 = i * 32 + (tid >> 3);           // packed lds row 0..63
    int ch = tid & 7;
    int lch = ch ^ (lr2 & 7);                // logical chunk at this slot
    int grow = lr2 * 2 + (lch >> 2);         // global row 0..127
    gload16(src + (size_t)grow * H_ + (lch & 3) * 8, dst + lr2 * 64 + ch * 8);
  }
}

__global__ __launch_bounds__(256, 2) void qkv_kernel(
    const u16* __restrict__ xn, const u16* __restrict__ w16,
    const float* __restrict__ dc, u16* __restrict__ Qb, u16* __restrict__ Kb,
    u16* __restrict__ VT, u16* __restrict__ vfl) {
  __shared__ u16 ldsA[3][2][64 * 64];   // [buf][row-half][packed 128r x 32c]
  __shared__ u16 ldsB[3][64 * 64];
  int bm = blockIdx.x;   // 32
  int bn = blockIdx.y;   // 24
  const u16* A  = xn + (size_t)bm * 256 * H_;
  const u16* Bp = w16 + (size_t)bn * 128 * H_;
  int tid = threadIdx.x;
  int l = tid & 63, w = tid >> 6;
  int wr = w >> 1, wc = w & 1;
  int lrow = l & 15, kc = l >> 4;
  f32x4 acc[8][4] = {};
  // prologue: tiles 0,1 -> bufs 0,1 (6 loads/thread each)
  stageBlk(A,                    ldsA[0][0], tid);
  stageBlk(A + (size_t)128 * H_, ldsA[0][1], tid);
  stageBlk(Bp,                   ldsB[0],    tid);
  stageBlk(A + 32,                    ldsA[1][0], tid);
  stageBlk(A + (size_t)128 * H_ + 32, ldsA[1][1], tid);
  stageBlk(Bp + 32,                   ldsB[1],    tid);
  asm volatile("s_waitcnt vmcnt(6)" ::: "memory");   // tile 0 landed
  __builtin_amdgcn_s_barrier();
  int bufc = 0;
  for (int t = 0; t < 32; ++t) {
    if (t + 2 < 32) {
      int nb = bufc + 2; if (nb >= 3) nb -= 3;
      const u16* As = A + (t + 2) * 32;
      stageBlk(As,                    ldsA[nb][0], tid);
      stageBlk(As + (size_t)128 * H_, ldsA[nb][1], tid);
      stageBlk(Bp + (t + 2) * 32,     ldsB[nb],    tid);
    }
    const u16* At = ldsA[bufc][wr];
    const u16* Bt = ldsB[bufc];
    bf16x8 bfr[4];
#pragma unroll
    for (int i = 0; i < 4; i++) {
      int y = wc * 64 + i * 16 + lrow;
      int ch = (((y & 1) << 2) | kc) ^ ((y >> 1) & 7);
      bfr[i] = *(const bf16x8*)&Bt[(y >> 1) * 64 + ch * 8];
    }
    __builtin_amdgcn_s_setprio(1);
#pragma unroll
    for (int mi = 0; mi < 8; mi++) {
      int x = mi * 16 + lrow;
      int ch = (((x & 1) << 2) | kc) ^ ((x >> 1) & 7);
      bf16x8 af = *(const bf16x8*)&At[(x >> 1) * 64 + ch * 8];
#pragma unroll
      for (int ni = 0; ni < 4; ni++)
        acc[mi][ni] = MFMA(af, bfr[ni], acc[mi][ni]);
    }
    __builtin_amdgcn_s_setprio(0);
    if (t + 2 < 32) {
      asm volatile("s_waitcnt vmcnt(6)" ::: "memory");  // tile t+1 landed
    } else if (t == 30) {
      asm volatile("s_waitcnt vmcnt(0)" ::: "memory");  // drain last tile
    }
    __builtin_amdgcn_s_barrier();
    bufc = (bufc == 2) ? 0 : bufc + 1;
  }
  // epilogue
  int wsel = bn >> 3;
  int col0 = (bn & 7) * 128 + wc * 64;
  int row0 = bm * 256 + wr * 128;
  const float* dcw = dc + (size_t)wsel * B_ * H_;
  float extra = (wsel == 0) ? 0.125f * L2E : 1.0f;
#pragma unroll
  for (int mi = 0; mi < 8; mi++) {
    int row = row0 + mi * 16 + (l >> 4) * 4;
    int b = row >> 10, s_base = row & 1023;
#pragma unroll
    for (int ni = 0; ni < 4; ni++) {
      int col = col0 + ni * 16 + (l & 15);
      int hh = col >> 6, dd = col & 63;
      float dcv = dcw[b * H_ + col] * extra;
      u16 bv[4];
#pragma unroll
      for (int rr = 0; rr < 4; rr++)
        bv[rr] = f2bf(acc[mi][ni][rr] * dcv);
      if (wsel == 0) {
#pragma unroll
        for (int rr = 0; rr < 4; rr++)
          Qb[((size_t)(b * NH + hh) * S_ + s_base + rr) * DH + dd] = bv[rr];
      } else if (wsel == 1) {
#pragma unroll
        for (int rr = 0; rr < 4; rr++)
          Kb[((size_t)(b * NH + hh) * S_ + s_base + rr) * DH + dd] = bv[rr];
      } else {
        u16x4 pv = { bv[0], bv[1], bv[2], bv[3] };
        *(u16x4*)&VT[((size_t)(b * NH + hh) * DH + dd) * S_ + s_base] = pv;
#pragma unroll
        for (int rr = 0; rr < 4; rr++)
          vfl[(size_t)(row + rr) * H_ + col] = bv[rr];
      }
    }
  }
}

// ---------------- 128x128 NT GEMM core (m97-style, measured-best at 256thr)
__device__ __forceinline__ void gemm128_core(
    const u16* __restrict__ Arow, const u16* __restrict__ Brow, int K,
    u16* ldsA, u16* ldsB, f32x4 acc[4][4]) {
  const int tid = threadIdx.x;
  const int l = tid & 63, w = tid >> 6;
  const int wm = (w >> 1) * 64, wn = (w & 1) * 64;
  const int lrow = l & 15, lko = (l >> 4) * 8;
  const int srow = tid >> 2;
  const int scol = (tid & 3) * 8;
  for (int k0 = 0; k0 < K; k0 += 32) {
    __syncthreads();
    gload16(Arow + (size_t)srow * K + k0 + scol,        ldsA + srow * 32 + scol);
    gload16(Arow + (size_t)(srow + 64) * K + k0 + scol, ldsA + (srow + 64) * 32 + scol);
    gload16(Brow + (size_t)srow * K + k0 + scol,        ldsB + srow * 32 + scol);
    gload16(Brow + (size_t)(srow + 64) * K + k0 + scol, ldsB + (srow + 64) * 32 + scol);
    __syncthreads();
    bf16x8 af[4], bfr[4];
#pragma unroll
    for (int i = 0; i < 4; i++)
      af[i] = *(const bf16x8*)&ldsA[(wm + i * 16 + lrow) * 32 + lko];
#pragma unroll
    for (int i = 0; i < 4; i++)
      bfr[i] = *(const bf16x8*)&ldsB[(wn + i * 16 + lrow) * 32 + lko];
#pragma unroll
    for (int mi = 0; mi < 4; mi++)
#pragma unroll
      for (int ni = 0; ni < 4; ni++)
        acc[mi][ni] = MFMA(af[mi], bfr[ni], acc[mi][ni]);
  }
}

// ---------------- flash attention, 32x32 MFMA + in-register P (T12)
__global__ __launch_bounds__(512) void attn_kernel(
    const u16* __restrict__ Qb, const u16* __restrict__ Kb,
    const u16* __restrict__ VT, u16* __restrict__ xat) {
  __shared__ u16 ldsK[3][64 * 64];
  __shared__ u16 ldsV[3][64 * 64];
  int tid = threadIdx.x;
  int l = tid & 63, w = tid >> 6;   // 8 waves, 32 q-rows each
  int id = blockIdx.x;
  int r = id & 7, rest = id >> 3;
  int qblk = rest & 3, a = rest >> 2;
  int hl = a * 8 + r;              // XCD-locality: same head -> same XCD
  int h = hl & 15, b = hl >> 4;
  int q0 = qblk * 256 + w * 32;
  const u16* Qp = Qb + ((size_t)(b * NH + h) * S_ + q0) * DH;
  const u16* Kp = Kb + (size_t)(b * NH + h) * S_ * DH;
  const u16* Vp = VT + (size_t)(b * NH + h) * DH * S_;
  int lq = l & 31, hi = l >> 5;
  int srow = tid >> 3, schunk = tid & 7;
  int ssw = (schunk * 8) ^ ((srow & 7) << 3);
  const u16* Ksrc = Kp + (size_t)srow * DH + ssw;
  const u16* Vsrc = Vp + (size_t)srow * S_ + ssw;
  int sdst = srow * 64 + schunk * 8;
  gload16(Ksrc, &ldsK[0][sdst]);
  gload16(Vsrc, &ldsV[0][sdst]);
  gload16(Ksrc + 64 * DH, &ldsK[1][sdst]);
  gload16(Vsrc + 64,      &ldsV[1][sdst]);
  bf16x8 qf[4];
#pragma unroll
  for (int s = 0; s < 4; s++)
    qf[s] = *(const bf16x8*)(Qp + lq * 64 + s * 16 + hi * 8);
  f32x16 acc0 = {}, acc1 = {};   // OUT^T d-blocks 0..31 / 32..63
  float ls = 0.f;
  asm volatile("s_waitcnt vmcnt(2)" ::: "memory");
  __builtin_amdgcn_s_barrier();
  int cur = 0;
  for (int t = 0; t < 16; ++t) {
    if (t + 2 < 16) {
      int nb = cur + 2; if (nb >= 3) nb -= 3;
      gload16(Ksrc + (size_t)(t + 2) * 64 * DH, &ldsK[nb][sdst]);
      gload16(Vsrc + (size_t)(t + 2) * 64,      &ldsV[nb][sdst]);
    }
    const u16* Kt = &ldsK[cur][0];
    const u16* Vt = &ldsV[cur][0];
    f32x16 z0 = {}, z1 = {};
    __builtin_amdgcn_s_setprio(1);
#pragma unroll
    for (int s = 0; s < 4; s++) {
      int ch = ((s * 2 + hi) ^ (lq & 7)) * 8;
      bf16x8 kf0 = *(const bf16x8*)&Kt[lq * 64 + ch];
      bf16x8 kf1 = *(const bf16x8*)&Kt[(32 + lq) * 64 + ch];
      z0 = MFMA32(kf0, qf[s], z0);
      z1 = MFMA32(kf1, qf[s], z1);
    }
    __builtin_amdgcn_s_setprio(0);
    float rs = 0.f;
#pragma unroll
    for (int i = 0; i < 16; i++) {
      z0[i] = __builtin_exp2f(z0[i]); rs += z0[i];
      z1[i] = __builtin_exp2f(z1[i]); rs += z1[i];
    }
    rs += __shfl_xor(rs, 32);
    ls += rs;
    bf16x8 pf[4];
#pragma unroll
    for (int g = 0; g < 2; g++) {
      unsigned pa = packbf2(z0[g * 8 + 0], z0[g * 8 + 1]);
      unsigned pb = packbf2(z0[g * 8 + 2], z0[g * 8 + 3]);
      unsigned pc = packbf2(z0[g * 8 + 4], z0[g * 8 + 5]);
      unsigned pd = packbf2(z0[g * 8 + 6], z0[g * 8 + 7]);
      u32x2 sA = __builtin_amdgcn_permlane32_swap(pa, pc, false, false);
      u32x2 sB = __builtin_amdgcn_permlane32_swap(pb, pd, false, false);
      union { unsigned u[4]; bf16x8 v; } uu;
      uu.u[0] = sA[0]; uu.u[1] = sB[0]; uu.u[2] = sA[1]; uu.u[3] = sB[1];
      pf[g] = uu.v;
    }
#pragma unroll
    for (int g = 0; g < 2; g++) {
      unsigned pa = packbf2(z1[g * 8 + 0], z1[g * 8 + 1]);
      unsigned pb = packbf2(z1[g * 8 + 2], z1[g * 8 + 3]);
      unsigned pc = packbf2(z1[g * 8 + 4], z1[g * 8 + 5]);
      unsigned pd = packbf2(z1[g * 8 + 6], z1[g * 8 + 7]);
      u32x2 sA = __builtin_amdgcn_permlane32_swap(pa, pc, false, false);
      u32x2 sB = __builtin_amdgcn_permlane32_swap(pb, pd, false, false);
      union { unsigned u[4]; bf16x8 v; } uu;
      uu.u[0] = sA[0]; uu.u[1] = sB[0]; uu.u[2] = sA[1]; uu.u[3] = sB[1];
      pf[2 + g] = uu.v;
    }
    __builtin_amdgcn_s_setprio(1);
#pragma unroll
    for (int ks = 0; ks < 4; ks++) {
      int ch = ((ks * 2 + hi) ^ (lq & 7)) * 8;
      bf16x8 vf0 = *(const bf16x8*)&Vt[lq * 64 + ch];
      bf16x8 vf1 = *(const bf16x8*)&Vt[(32 + lq) * 64 + ch];
      acc0 = MFMA32(vf0, pf[ks], acc0);
      acc1 = MFMA32(vf1, pf[ks], acc1);
    }
    __builtin_amdgcn_s_setprio(0);
    if (t < 14) {
      asm volatile("s_waitcnt vmcnt(2)" ::: "memory");
    } else if (t == 14) {
      asm volatile("s_waitcnt vmcnt(0)" ::: "memory");
    }
    if (t < 15) __builtin_amdgcn_s_barrier();
    cur = (cur == 2) ? 0 : cur + 1;
  }
  float inv = 1.f / ls;
  size_t orow = ((size_t)b * S_ + q0 + lq) * H_ + h * DH;
#pragma unroll
  for (int g = 0; g < 4; g++) {
    int d0 = g * 8 + hi * 4;
    u16x4 o0 = { f2bf(acc0[g * 4 + 0] * inv), f2bf(acc0[g * 4 + 1] * inv),
                 f2bf(acc0[g * 4 + 2] * inv), f2bf(acc0[g * 4 + 3] * inv) };
    *(u16x4*)(xat + orow + d0) = o0;
    u16x4 o1 = { f2bf(acc1[g * 4 + 0] * inv), f2bf(acc1[g * 4 + 1] * inv),
                 f2bf(acc1[g * 4 + 2] * inv), f2bf(acc1[g * 4 + 3] * inv) };
    *(u16x4*)(xat + orow + 32 + d0) = o1;
  }
}

// ---------------- out GEMM: (xat@W^T)*wdc + (vfl@U^T)*udc, f32 out
__global__ __launch_bounds__(256) void out_kernel(
    const u16* __restrict__ xat, const u16* __restrict__ vfl,
    const u16* __restrict__ w16, const float* __restrict__ dc,
    float* __restrict__ out) {
  __shared__ u16 ldsA[128 * 32], ldsB[128 * 32];
  int bm = blockIdx.x;   // 64
  int bn = blockIdx.y;   // 8
  f32x4 acc[4][4] = {};
  gemm128_core(xat + (size_t)bm * 128 * H_,
               w16 + (size_t)3 * H_ * H_ + (size_t)bn * 128 * H_, H_,
               ldsA, ldsB, acc);
  int l = threadIdx.x & 63, w = threadIdx.x >> 6;
  int wm = (w >> 1) * 64, wn = (w & 1) * 64;
  int col0 = bn * 128 + wn;
  int row0 = bm * 128 + wm;
  int b = row0 >> 10;
  const float* wdc = dc + (size_t)3 * B_ * H_ + b * H_;
  const float* udc = dc + (size_t)4 * B_ * H_ + b * H_;
  float ratio[4], ud[4];
#pragma unroll
  for (int ni = 0; ni < 4; ni++) {
    int col = col0 + ni * 16 + (l & 15);
    ud[ni] = udc[col];
    ratio[ni] = wdc[col] / ud[ni];
  }
#pragma unroll
  for (int mi = 0; mi < 4; mi++)
#pragma unroll
    for (int ni = 0; ni < 4; ni++)
#pragma unroll
      for (int rr = 0; rr < 4; rr++) acc[mi][ni][rr] *= ratio[ni];
  gemm128_core(vfl + (size_t)bm * 128 * H_,
               w16 + (size_t)4 * H_ * H_ + (size_t)bn * 128 * H_, H_,
               ldsA, ldsB, acc);
#pragma unroll
  for (int mi = 0; mi < 4; mi++)
#pragma unroll
    for (int ni = 0; ni < 4; ni++) {
      int col = col0 + ni * 16 + (l & 15);
#pragma unroll
      for (int rr = 0; rr < 4; rr++) {
        int row = row0 + mi * 16 + (l >> 4) * 4 + rr;
        out[(size_t)row * H_ + col] = acc[mi][ni][rr] * ud[ni];
      }
    }
}

extern "C" void kernel_launch(void* const* d_in, const int* in_sizes, int n_in,
                              void* d_out, int out_size, void* d_ws, size_t ws_size,
                              hipStream_t stream) {
  const float* x = (const float*)d_in[0];
  const float* qw = (const float*)d_in[1];
  const float* kw = (const float*)d_in[2];
  const float* vw = (const float*)d_in[3];
  const float* ww = (const float*)d_in[4];
  const float* uw = (const float*)d_in[5];
  const float* styles = (const float*)d_in[6];
  float* out = (float*)d_out;

  char* ws = (char*)d_ws;
  size_t need = 163840 + (size_t)5 * H_ * H_ * 2 + (size_t)6 * BS * H_ * 2;
  if (ws_size < need) return;
  float* dc = (float*)ws;
  u16* w16 = (u16*)(ws + 163840);
  u16* xn  = w16 + (size_t)5 * H_ * H_;
  u16* Qb  = xn + (size_t)BS * H_;
  u16* Kb  = Qb + (size_t)BS * H_;
  u16* VT  = Kb + (size_t)BS * H_;
  u16* vfl = VT + (size_t)BS * H_;
  u16* xat = vfl + (size_t)BS * H_;

  dcoef_kernel<<<dim3(5 * H_), dim3(256), 0, stream>>>(qw, kw, vw, ww, uw, styles, dc, w16);
  ln_kernel<<<dim3(BS), dim3(256), 0, stream>>>(x, styles, xn);
  qkv_kernel<<<dim3(32, 24), dim3(256), 0, stream>>>(xn, w16, dc, Qb, Kb, VT, vfl);
  attn_kernel<<<dim3(512), dim3(512), 0, stream>>>(Qb, Kb, VT, xat);
  out_kernel<<<dim3(64, 8), dim3(256), 0, stream>>>(xat, vfl, w16, dc, out);
}

// Round 11
// 205.876 us; speedup vs baseline: 1.0323x; 1.0249x over previous
//
#include <hip/hip_runtime.h>
#include <hip/hip_bf16.h>

#define B_ 8
#define S_ 1024
#define H_ 1024
#define NH 16
#define DH 64
#define BS (B_*S_)
#define L2E 1.44269504f

typedef unsigned short u16;
typedef __attribute__((ext_vector_type(8))) short bf16x8;
typedef __attribute__((ext_vector_type(4))) float f32x4;
typedef __attribute__((ext_vector_type(16))) float f32x16;
typedef __attribute__((ext_vector_type(4))) u16 u16x4;
typedef __attribute__((ext_vector_type(2))) unsigned int u32x2;

#define MFMA(a,b,c)   __builtin_amdgcn_mfma_f32_16x16x32_bf16((a),(b),(c),0,0,0)
#define MFMA32(a,b,c) __builtin_amdgcn_mfma_f32_32x32x16_bf16((a),(b),(c),0,0,0)

__device__ __forceinline__ u16 f2bf(float f) {
  union { float f; unsigned u; } v; v.f = f;
  unsigned r = v.u + 0x7fffu + ((v.u >> 16) & 1u);
  return (u16)(r >> 16);
}

__device__ __forceinline__ unsigned packbf2(float a, float b) {
  union { __hip_bfloat162 h; unsigned u; } v;
  v.h = __float22bfloat162_rn(float2{a, b});
  return v.u;
}

__device__ __forceinline__ void gload16(const u16* g, u16* l) {
  __builtin_amdgcn_global_load_lds(
      (const __attribute__((address_space(1))) unsigned int*)g,
      (__attribute__((address_space(3))) unsigned int*)l, 16, 0, 0);
}

// ---------------- dcoef (+ fused weight f32->bf16 conversion)
__global__ __launch_bounds__(256) void dcoef_kernel(
    const float* __restrict__ qw, const float* __restrict__ kw,
    const float* __restrict__ vw, const float* __restrict__ ww,
    const float* __restrict__ uw, const float* __restrict__ styles,
    float* __restrict__ dc, u16* __restrict__ w16) {
  int bi = blockIdx.x;            // 5*1024
  int wsel = bi >> 10;
  int o = bi & 1023;
  const float* W = (wsel == 0) ? qw : (wsel == 1) ? kw : (wsel == 2) ? vw
                   : (wsel == 3) ? ww : uw;
  int soff = (wsel < 3) ? 0 : H_;
  int tid = threadIdx.x;
  float4 w4 = *(const float4*)(W + (size_t)o * H_ + tid * 4);
  u16x4 wo = { f2bf(w4.x), f2bf(w4.y), f2bf(w4.z), f2bf(w4.w) };
  *(u16x4*)(w16 + (size_t)wsel * H_ * H_ + (size_t)o * H_ + tid * 4) = wo;
  float w2x = w4.x * w4.x, w2y = w4.y * w4.y, w2z = w4.z * w4.z, w2w = w4.w * w4.w;
  float acc[8];
#pragma unroll
  for (int b = 0; b < 8; b++) {
    float4 s4 = *(const float4*)(styles + (size_t)b * 2 * H_ + soff + tid * 4);
    acc[b] = w2x * s4.x * s4.x + w2y * s4.y * s4.y + w2z * s4.z * s4.z + w2w * s4.w * s4.w;
  }
#pragma unroll
  for (int off = 1; off < 64; off <<= 1)
#pragma unroll
    for (int b = 0; b < 8; b++) acc[b] += __shfl_xor(acc[b], off);
  __shared__ float red[4][8];
  int w = tid >> 6, l = tid & 63;
  if (l == 0)
#pragma unroll
    for (int b = 0; b < 8; b++) red[w][b] = acc[b];
  __syncthreads();
  if (tid < 8) {
    int b = tid;
    float v = red[0][b] + red[1][b] + red[2][b] + red[3][b];
    float r = rsqrtf(v + 1e-8f);
    if (wsel == 2) r *= styles[(size_t)b * 2 * H_ + H_ + o];
    dc[(size_t)wsel * B_ * H_ + b * H_ + o] = r;
  }
}

// ---------------- style-scale + layernorm, bf16 out
__global__ __launch_bounds__(256) void ln_kernel(
    const float* __restrict__ x, const float* __restrict__ styles,
    u16* __restrict__ xn) {
  int row = blockIdx.x;        // 8192
  int b = row >> 10;
  int tid = threadIdx.x;
  const float4 xv = *(const float4*)(x + (size_t)row * H_ + tid * 4);
  const float4 sv = *(const float4*)(styles + (size_t)b * 2 * H_ + tid * 4);
  float v0 = xv.x * sv.x, v1 = xv.y * sv.y, v2 = xv.z * sv.z, v3 = xv.w * sv.w;
  float sum = v0 + v1 + v2 + v3;
  float sq = v0 * v0 + v1 * v1 + v2 * v2 + v3 * v3;
#pragma unroll
  for (int off = 1; off < 64; off <<= 1) {
    sum += __shfl_xor(sum, off);
    sq += __shfl_xor(sq, off);
  }
  __shared__ float rsum[4], rsq[4];
  int w = tid >> 6;
  if ((tid & 63) == 0) { rsum[w] = sum; rsq[w] = sq; }
  __syncthreads();
  sum = rsum[0] + rsum[1] + rsum[2] + rsum[3];
  sq = rsq[0] + rsq[1] + rsq[2] + rsq[3];
  float mean = sum * (1.f / H_);
  float var = sq * (1.f / H_) - mean * mean;
  float rstd = rsqrtf(var + 1e-5f);
  u16x4 o = { f2bf((v0 - mean) * rstd), f2bf((v1 - mean) * rstd),
              f2bf((v2 - mean) * rstd), f2bf((v3 - mean) * rstd) };
  *(u16x4*)(xn + (size_t)row * H_ + tid * 4) = o;
}

// ---------------- 128x128 NT GEMM core (m97-style, measured-best: R8 73.5us)
__device__ __forceinline__ void gemm128_core(
    const u16* __restrict__ Arow, const u16* __restrict__ Brow, int K,
    u16* ldsA, u16* ldsB, f32x4 acc[4][4]) {
  const int tid = threadIdx.x;
  const int l = tid & 63, w = tid >> 6;
  const int wm = (w >> 1) * 64, wn = (w & 1) * 64;
  const int lrow = l & 15, lko = (l >> 4) * 8;
  const int srow = tid >> 2;
  const int scol = (tid & 3) * 8;
  for (int k0 = 0; k0 < K; k0 += 32) {
    __syncthreads();
    gload16(Arow + (size_t)srow * K + k0 + scol,        ldsA + srow * 32 + scol);
    gload16(Arow + (size_t)(srow + 64) * K + k0 + scol, ldsA + (srow + 64) * 32 + scol);
    gload16(Brow + (size_t)srow * K + k0 + scol,        ldsB + srow * 32 + scol);
    gload16(Brow + (size_t)(srow + 64) * K + k0 + scol, ldsB + (srow + 64) * 32 + scol);
    __syncthreads();
    bf16x8 af[4], bfr[4];
#pragma unroll
    for (int i = 0; i < 4; i++)
      af[i] = *(const bf16x8*)&ldsA[(wm + i * 16 + lrow) * 32 + lko];
#pragma unroll
    for (int i = 0; i < 4; i++)
      bfr[i] = *(const bf16x8*)&ldsB[(wn + i * 16 + lrow) * 32 + lko];
#pragma unroll
    for (int mi = 0; mi < 4; mi++)
#pragma unroll
      for (int ni = 0; ni < 4; ni++)
        acc[mi][ni] = MFMA(af[mi], bfr[ni], acc[mi][ni]);
  }
}

// ---------------- QKV GEMM: xn[8192,1024] @ w16[0..3072][1024]^T (R8 config)
__global__ __launch_bounds__(256) void qkv_kernel(
    const u16* __restrict__ xn, const u16* __restrict__ w16,
    const float* __restrict__ dc, u16* __restrict__ Qb, u16* __restrict__ Kb,
    u16* __restrict__ VT, u16* __restrict__ vfl) {
  __shared__ u16 ldsA[128 * 32], ldsB[128 * 32];
  int bm = blockIdx.x;   // 64
  int bn = blockIdx.y;   // 24
  f32x4 acc[4][4] = {};
  gemm128_core(xn + (size_t)bm * 128 * H_, w16 + (size_t)bn * 128 * H_, H_,
               ldsA, ldsB, acc);
  int l = threadIdx.x & 63, w = threadIdx.x >> 6;
  int wm = (w >> 1) * 64, wn = (w & 1) * 64;
  int wsel = bn >> 3;
  int col0 = (bn & 7) * 128 + wn;
  int row0 = bm * 128 + wm;
  const float* dcw = dc + (size_t)wsel * B_ * H_;
  // fold 1/sqrt(d) and log2(e) into Q so attention can use raw exp2
  float extra = (wsel == 0) ? 0.125f * L2E : 1.0f;
#pragma unroll
  for (int mi = 0; mi < 4; mi++) {
#pragma unroll
    for (int ni = 0; ni < 4; ni++) {
      int col = col0 + ni * 16 + (l & 15);
      int hh = col >> 6, dd = col & 63;
      int s_base = (row0 + mi * 16 + (l >> 4) * 4) & 1023;
      int b = (row0 + mi * 16 + (l >> 4) * 4) >> 10;
      float dcv = dcw[b * H_ + col] * extra;
      u16 bv[4];
#pragma unroll
      for (int rr = 0; rr < 4; rr++)
        bv[rr] = f2bf(acc[mi][ni][rr] * dcv);
      if (wsel == 0) {
#pragma unroll
        for (int rr = 0; rr < 4; rr++)
          Qb[((size_t)(b * NH + hh) * S_ + s_base + rr) * DH + dd] = bv[rr];
      } else if (wsel == 1) {
#pragma unroll
        for (int rr = 0; rr < 4; rr++)
          Kb[((size_t)(b * NH + hh) * S_ + s_base + rr) * DH + dd] = bv[rr];
      } else {
        u16x4 pv = { bv[0], bv[1], bv[2], bv[3] };
        *(u16x4*)&VT[((size_t)(b * NH + hh) * DH + dd) * S_ + s_base] = pv;
#pragma unroll
        for (int rr = 0; rr < 4; rr++)
          vfl[(size_t)(row0 + mi * 16 + (l >> 4) * 4 + rr) * H_ + col] = bv[rr];
      }
    }
  }
}

// ---------------- flash attention, 32x32 MFMA, 64 q-rows/wave:
// two 32-row groups (A/B) share every K/V ds_read_b128 -> LDS traffic per
// q-row halves vs R8. In-register P (cvt_pk + permlane32_swap), fixed-max
// softmax, 3-buf K/V staging, depth-2 prefetch, counted vmcnt.
// Grid 256 = 1 block/CU; head's 2 blocks 128 apart -> same XCD (id%8 equal).
__global__ __launch_bounds__(512) void attn_kernel(
    const u16* __restrict__ Qb, const u16* __restrict__ Kb,
    const u16* __restrict__ VT, u16* __restrict__ xat) {
  __shared__ u16 ldsK[3][64 * 64];
  __shared__ u16 ldsV[3][64 * 64];
  int tid = threadIdx.x;
  int l = tid & 63, w = tid >> 6;   // 8 waves, 64 q-rows each
  int id = blockIdx.x;              // 256
  int qblk = id >> 7;               // 0..1
  int hl = id & 127;
  int h = hl & 15, b = hl >> 4;
  int q0 = qblk * 512 + w * 64;
  const u16* Qp = Qb + ((size_t)(b * NH + h) * S_ + q0) * DH;
  const u16* Kp = Kb + (size_t)(b * NH + h) * S_ * DH;
  const u16* Vp = VT + (size_t)(b * NH + h) * DH * S_;
  int lq = l & 31, hi = l >> 5;
  int srow = tid >> 3, schunk = tid & 7;
  int ssw = (schunk * 8) ^ ((srow & 7) << 3);
  const u16* Ksrc = Kp + (size_t)srow * DH + ssw;
  const u16* Vsrc = Vp + (size_t)srow * S_ + ssw;
  int sdst = srow * 64 + schunk * 8;
  gload16(Ksrc, &ldsK[0][sdst]);
  gload16(Vsrc, &ldsV[0][sdst]);
  gload16(Ksrc + 64 * DH, &ldsK[1][sdst]);
  gload16(Vsrc + 64,      &ldsV[1][sdst]);
  // Q fragments for both 32-row groups
  bf16x8 qfA[4], qfB[4];
#pragma unroll
  for (int s = 0; s < 4; s++) {
    qfA[s] = *(const bf16x8*)(Qp + lq * 64 + s * 16 + hi * 8);
    qfB[s] = *(const bf16x8*)(Qp + (32 + lq) * 64 + s * 16 + hi * 8);
  }
  f32x16 acc0A = {}, acc1A = {}, acc0B = {}, acc1B = {};
  float lsA = 0.f, lsB = 0.f;
  asm volatile("s_waitcnt vmcnt(2)" ::: "memory");
  __builtin_amdgcn_s_barrier();
  int cur = 0;
  for (int t = 0; t < 16; ++t) {
    if (t + 2 < 16) {
      int nb = cur + 2; if (nb >= 3) nb -= 3;
      gload16(Ksrc + (size_t)(t + 2) * 64 * DH, &ldsK[nb][sdst]);
      gload16(Vsrc + (size_t)(t + 2) * 64,      &ldsV[nb][sdst]);
    }
    const u16* Kt = &ldsK[cur][0];
    const u16* Vt = &ldsV[cur][0];
    // QK^T for both groups; each kf read feeds 2 MFMA
    f32x16 z0A = {}, z1A = {}, z0B = {}, z1B = {};
    __builtin_amdgcn_s_setprio(1);
#pragma unroll
    for (int s = 0; s < 4; s++) {
      int ch = ((s * 2 + hi) ^ (lq & 7)) * 8;
      bf16x8 kf0 = *(const bf16x8*)&Kt[lq * 64 + ch];
      bf16x8 kf1 = *(const bf16x8*)&Kt[(32 + lq) * 64 + ch];
      z0A = MFMA32(kf0, qfA[s], z0A);
      z1A = MFMA32(kf1, qfA[s], z1A);
      z0B = MFMA32(kf0, qfB[s], z0B);
      z1B = MFMA32(kf1, qfB[s], z1B);
    }
    __builtin_amdgcn_s_setprio(0);
    float rsA = 0.f, rsB = 0.f;
#pragma unroll
    for (int i = 0; i < 16; i++) {
      z0A[i] = __builtin_exp2f(z0A[i]); rsA += z0A[i];
      z1A[i] = __builtin_exp2f(z1A[i]); rsA += z1A[i];
      z0B[i] = __builtin_exp2f(z0B[i]); rsB += z0B[i];
      z1B[i] = __builtin_exp2f(z1B[i]); rsB += z1B[i];
    }
    rsA += __shfl_xor(rsA, 32); lsA += rsA;
    rsB += __shfl_xor(rsB, 32); lsB += rsB;
    // in-register P -> bf16 B-fragments (cvt_pk + permlane32_swap)
    bf16x8 pfA[4], pfB[4];
#pragma unroll
    for (int g = 0; g < 2; g++) {
      {
        unsigned pa = packbf2(z0A[g * 8 + 0], z0A[g * 8 + 1]);
        unsigned pb = packbf2(z0A[g * 8 + 2], z0A[g * 8 + 3]);
        unsigned pc = packbf2(z0A[g * 8 + 4], z0A[g * 8 + 5]);
        unsigned pd = packbf2(z0A[g * 8 + 6], z0A[g * 8 + 7]);
        u32x2 sA = __builtin_amdgcn_permlane32_swap(pa, pc, false, false);
        u32x2 sB = __builtin_amdgcn_permlane32_swap(pb, pd, false, false);
        union { unsigned u[4]; bf16x8 v; } uu;
        uu.u[0] = sA[0]; uu.u[1] = sB[0]; uu.u[2] = sA[1]; uu.u[3] = sB[1];
        pfA[g] = uu.v;
      }
      {
        unsigned pa = packbf2(z1A[g * 8 + 0], z1A[g * 8 + 1]);
        unsigned pb = packbf2(z1A[g * 8 + 2], z1A[g * 8 + 3]);
        unsigned pc = packbf2(z1A[g * 8 + 4], z1A[g * 8 + 5]);
        unsigned pd = packbf2(z1A[g * 8 + 6], z1A[g * 8 + 7]);
        u32x2 sA = __builtin_amdgcn_permlane32_swap(pa, pc, false, false);
        u32x2 sB = __builtin_amdgcn_permlane32_swap(pb, pd, false, false);
        union { unsigned u[4]; bf16x8 v; } uu;
        uu.u[0] = sA[0]; uu.u[1] = sB[0]; uu.u[2] = sA[1]; uu.u[3] = sB[1];
        pfA[2 + g] = uu.v;
      }
      {
        unsigned pa = packbf2(z0B[g * 8 + 0], z0B[g * 8 + 1]);
        unsigned pb = packbf2(z0B[g * 8 + 2], z0B[g * 8 + 3]);
        unsigned pc = packbf2(z0B[g * 8 + 4], z0B[g * 8 + 5]);
        unsigned pd = packbf2(z0B[g * 8 + 6], z0B[g * 8 + 7]);
        u32x2 sA = __builtin_amdgcn_permlane32_swap(pa, pc, false, false);
        u32x2 sB = __builtin_amdgcn_permlane32_swap(pb, pd, false, false);
        union { unsigned u[4]; bf16x8 v; } uu;
        uu.u[0] = sA[0]; uu.u[1] = sB[0]; uu.u[2] = sA[1]; uu.u[3] = sB[1];
        pfB[g] = uu.v;
      }
      {
        unsigned pa = packbf2(z1B[g * 8 + 0], z1B[g * 8 + 1]);
        unsigned pb = packbf2(z1B[g * 8 + 2], z1B[g * 8 + 3]);
        unsigned pc = packbf2(z1B[g * 8 + 4], z1B[g * 8 + 5]);
        unsigned pd = packbf2(z1B[g * 8 + 6], z1B[g * 8 + 7]);
        u32x2 sA = __builtin_amdgcn_permlane32_swap(pa, pc, false, false);
        u32x2 sB = __builtin_amdgcn_permlane32_swap(pb, pd, false, false);
        union { unsigned u[4]; bf16x8 v; } uu;
        uu.u[0] = sA[0]; uu.u[1] = sB[0]; uu.u[2] = sA[1]; uu.u[3] = sB[1];
        pfB[2 + g] = uu.v;
      }
    }
    // PV for both groups; each vf read feeds 2 MFMA
    __builtin_amdgcn_s_setprio(1);
#pragma unroll
    for (int ks = 0; ks < 4; ks++) {
      int ch = ((ks * 2 + hi) ^ (lq & 7)) * 8;
      bf16x8 vf0 = *(const bf16x8*)&Vt[lq * 64 + ch];
      bf16x8 vf1 = *(const bf16x8*)&Vt[(32 + lq) * 64 + ch];
      acc0A = MFMA32(vf0, pfA[ks], acc0A);
      acc1A = MFMA32(vf1, pfA[ks], acc1A);
      acc0B = MFMA32(vf0, pfB[ks], acc0B);
      acc1B = MFMA32(vf1, pfB[ks], acc1B);
    }
    __builtin_amdgcn_s_setprio(0);
    if (t < 14) {
      asm volatile("s_waitcnt vmcnt(2)" ::: "memory");   // tile t+1 landed
    } else if (t == 14) {
      asm volatile("s_waitcnt vmcnt(0)" ::: "memory");   // drain tile 15
    }
    if (t < 15) __builtin_amdgcn_s_barrier();
    cur = (cur == 2) ? 0 : cur + 1;
  }
  float invA = 1.f / lsA, invB = 1.f / lsB;
  size_t orowA = ((size_t)b * S_ + q0 + lq) * H_ + h * DH;
  size_t orowB = orowA + (size_t)32 * H_;
#pragma unroll
  for (int g = 0; g < 4; g++) {
    int d0 = g * 8 + hi * 4;     // d = (reg&3) + 8*(reg>>2) + 4*hi
    u16x4 a0 = { f2bf(acc0A[g * 4 + 0] * invA), f2bf(acc0A[g * 4 + 1] * invA),
                 f2bf(acc0A[g * 4 + 2] * invA), f2bf(acc0A[g * 4 + 3] * invA) };
    *(u16x4*)(xat + orowA + d0) = a0;
    u16x4 a1 = { f2bf(acc1A[g * 4 + 0] * invA), f2bf(acc1A[g * 4 + 1] * invA),
                 f2bf(acc1A[g * 4 + 2] * invA), f2bf(acc1A[g * 4 + 3] * invA) };
    *(u16x4*)(xat + orowA + 32 + d0) = a1;
    u16x4 b0 = { f2bf(acc0B[g * 4 + 0] * invB), f2bf(acc0B[g * 4 + 1] * invB),
                 f2bf(acc0B[g * 4 + 2] * invB), f2bf(acc0B[g * 4 + 3] * invB) };
    *(u16x4*)(xat + orowB + d0) = b0;
    u16x4 b1 = { f2bf(acc1B[g * 4 + 0] * invB), f2bf(acc1B[g * 4 + 1] * invB),
                 f2bf(acc1B[g * 4 + 2] * invB), f2bf(acc1B[g * 4 + 3] * invB) };
    *(u16x4*)(xat + orowB + 32 + d0) = b1;
  }
}

// ---------------- out GEMM: (xat@W^T)*wdc + (vfl@U^T)*udc, f32 out (R8)
__global__ __launch_bounds__(256) void out_kernel(
    const u16* __restrict__ xat, const u16* __restrict__ vfl,
    const u16* __restrict__ w16, const float* __restrict__ dc,
    float* __restrict__ out) {
  __shared__ u16 ldsA[128 * 32], ldsB[128 * 32];
  int bm = blockIdx.x;   // 64
  int bn = blockIdx.y;   // 8
  f32x4 acc[4][4] = {};
  gemm128_core(xat + (size_t)bm * 128 * H_,
               w16 + (size_t)3 * H_ * H_ + (size_t)bn * 128 * H_, H_,
               ldsA, ldsB, acc);
  int l = threadIdx.x & 63, w = threadIdx.x >> 6;
  int wm = (w >> 1) * 64, wn = (w & 1) * 64;
  int col0 = bn * 128 + wn;
  int row0 = bm * 128 + wm;
  int b = row0 >> 10;
  const float* wdc = dc + (size_t)3 * B_ * H_ + b * H_;
  const float* udc = dc + (size_t)4 * B_ * H_ + b * H_;
  float ratio[4], ud[4];
#pragma unroll
  for (int ni = 0; ni < 4; ni++) {
    int col = col0 + ni * 16 + (l & 15);
    ud[ni] = udc[col];
    ratio[ni] = wdc[col] / ud[ni];
  }
#pragma unroll
  for (int mi = 0; mi < 4; mi++)
#pragma unroll
    for (int ni = 0; ni < 4; ni++)
#pragma unroll
      for (int rr = 0; rr < 4; rr++) acc[mi][ni][rr] *= ratio[ni];
  gemm128_core(vfl + (size_t)bm * 128 * H_,
               w16 + (size_t)4 * H_ * H_ + (size_t)bn * 128 * H_, H_,
               ldsA, ldsB, acc);
#pragma unroll
  for (int mi = 0; mi < 4; mi++)
#pragma unroll
    for (int ni = 0; ni < 4; ni++) {
      int col = col0 + ni * 16 + (l & 15);
#pragma unroll
      for (int rr = 0; rr < 4; rr++) {
        int row = row0 + mi * 16 + (l >> 4) * 4 + rr;
        out[(size_t)row * H_ + col] = acc[mi][ni][rr] * ud[ni];
      }
    }
}

extern "C" void kernel_launch(void* const* d_in, const int* in_sizes, int n_in,
                              void* d_out, int out_size, void* d_ws, size_t ws_size,
                              hipStream_t stream) {
  const float* x = (const float*)d_in[0];
  const float* qw = (const float*)d_in[1];
  const float* kw = (const float*)d_in[2];
  const float* vw = (const float*)d_in[3];
  const float* ww = (const float*)d_in[4];
  const float* uw = (const float*)d_in[5];
  const float* styles = (const float*)d_in[6];
  float* out = (float*)d_out;

  char* ws = (char*)d_ws;
  size_t need = 163840 + (size_t)5 * H_ * H_ * 2 + (size_t)6 * BS * H_ * 2;
  if (ws_size < need) return;
  float* dc = (float*)ws;
  u16* w16 = (u16*)(ws + 163840);
  u16* xn  = w16 + (size_t)5 * H_ * H_;
  u16* Qb  = xn + (size_t)BS * H_;
  u16* Kb  = Qb + (size_t)BS * H_;
  u16* VT  = Kb + (size_t)BS * H_;
  u16* vfl = VT + (size_t)BS * H_;
  u16* xat = vfl + (size_t)BS * H_;

  dcoef_kernel<<<dim3(5 * H_), dim3(256), 0, stream>>>(qw, kw, vw, ww, uw, styles, dc, w16);
  ln_kernel<<<dim3(BS), dim3(256), 0, stream>>>(x, styles, xn);
  qkv_kernel<<<dim3(64, 24), dim3(256), 0, stream>>>(xn, w16, dc, Qb, Kb, VT, vfl);
  attn_kernel<<<dim3(256), dim3(512), 0, stream>>>(Qb, Kb, VT, xat);
  out_kernel<<<dim3(64, 8), dim3(256), 0, stream>>>(xat, vfl, w16, dc, out);
}

// Round 12
// 204.791 us; speedup vs baseline: 1.0378x; 1.0053x over previous
//
#include <hip/hip_runtime.h>
#include <hip/hip_bf16.h>

#define B_ 8
#define S_ 1024
#define H_ 1024
#define NH 16
#define DH 64
#define BS (B_*S_)
#define L2E 1.44269504f

typedef unsigned short u16;
typedef __attribute__((ext_vector_type(8))) short bf16x8;
typedef __attribute__((ext_vector_type(4))) float f32x4;
typedef __attribute__((ext_vector_type(16))) float f32x16;
typedef __attribute__((ext_vector_type(4))) u16 u16x4;
typedef __attribute__((ext_vector_type(2))) unsigned int u32x2;

#define MFMA(a,b,c)   __builtin_amdgcn_mfma_f32_16x16x32_bf16((a),(b),(c),0,0,0)
#define MFMA32(a,b,c) __builtin_amdgcn_mfma_f32_32x32x16_bf16((a),(b),(c),0,0,0)

__device__ __forceinline__ u16 f2bf(float f) {
  union { float f; unsigned u; } v; v.f = f;
  unsigned r = v.u + 0x7fffu + ((v.u >> 16) & 1u);
  return (u16)(r >> 16);
}

__device__ __forceinline__ unsigned packbf2(float a, float b) {
  union { __hip_bfloat162 h; unsigned u; } v;
  v.h = __float22bfloat162_rn(float2{a, b});
  return v.u;
}

__device__ __forceinline__ void gload16(const u16* g, u16* l) {
  __builtin_amdgcn_global_load_lds(
      (const __attribute__((address_space(1))) unsigned int*)g,
      (__attribute__((address_space(3))) unsigned int*)l, 16, 0, 0);
}

// ---------------- dcoef (+ fused weight f32->bf16 conversion)
__global__ __launch_bounds__(256) void dcoef_kernel(
    const float* __restrict__ qw, const float* __restrict__ kw,
    const float* __restrict__ vw, const float* __restrict__ ww,
    const float* __restrict__ uw, const float* __restrict__ styles,
    float* __restrict__ dc, u16* __restrict__ w16) {
  int bi = blockIdx.x;            // 5*1024
  int wsel = bi >> 10;
  int o = bi & 1023;
  const float* W = (wsel == 0) ? qw : (wsel == 1) ? kw : (wsel == 2) ? vw
                   : (wsel == 3) ? ww : uw;
  int soff = (wsel < 3) ? 0 : H_;
  int tid = threadIdx.x;
  float4 w4 = *(const float4*)(W + (size_t)o * H_ + tid * 4);
  u16x4 wo = { f2bf(w4.x), f2bf(w4.y), f2bf(w4.z), f2bf(w4.w) };
  *(u16x4*)(w16 + (size_t)wsel * H_ * H_ + (size_t)o * H_ + tid * 4) = wo;
  float w2x = w4.x * w4.x, w2y = w4.y * w4.y, w2z = w4.z * w4.z, w2w = w4.w * w4.w;
  float acc[8];
#pragma unroll
  for (int b = 0; b < 8; b++) {
    float4 s4 = *(const float4*)(styles + (size_t)b * 2 * H_ + soff + tid * 4);
    acc[b] = w2x * s4.x * s4.x + w2y * s4.y * s4.y + w2z * s4.z * s4.z + w2w * s4.w * s4.w;
  }
#pragma unroll
  for (int off = 1; off < 64; off <<= 1)
#pragma unroll
    for (int b = 0; b < 8; b++) acc[b] += __shfl_xor(acc[b], off);
  __shared__ float red[4][8];
  int w = tid >> 6, l = tid & 63;
  if (l == 0)
#pragma unroll
    for (int b = 0; b < 8; b++) red[w][b] = acc[b];
  __syncthreads();
  if (tid < 8) {
    int b = tid;
    float v = red[0][b] + red[1][b] + red[2][b] + red[3][b];
    float r = rsqrtf(v + 1e-8f);
    if (wsel == 2) r *= styles[(size_t)b * 2 * H_ + H_ + o];
    dc[(size_t)wsel * B_ * H_ + b * H_ + o] = r;
  }
}

// ---------------- style-scale + layernorm, bf16 out
__global__ __launch_bounds__(256) void ln_kernel(
    const float* __restrict__ x, const float* __restrict__ styles,
    u16* __restrict__ xn) {
  int row = blockIdx.x;        // 8192
  int b = row >> 10;
  int tid = threadIdx.x;
  const float4 xv = *(const float4*)(x + (size_t)row * H_ + tid * 4);
  const float4 sv = *(const float4*)(styles + (size_t)b * 2 * H_ + tid * 4);
  float v0 = xv.x * sv.x, v1 = xv.y * sv.y, v2 = xv.z * sv.z, v3 = xv.w * sv.w;
  float sum = v0 + v1 + v2 + v3;
  float sq = v0 * v0 + v1 * v1 + v2 * v2 + v3 * v3;
#pragma unroll
  for (int off = 1; off < 64; off <<= 1) {
    sum += __shfl_xor(sum, off);
    sq += __shfl_xor(sq, off);
  }
  __shared__ float rsum[4], rsq[4];
  int w = tid >> 6;
  if ((tid & 63) == 0) { rsum[w] = sum; rsq[w] = sq; }
  __syncthreads();
  sum = rsum[0] + rsum[1] + rsum[2] + rsum[3];
  sq = rsq[0] + rsq[1] + rsq[2] + rsq[3];
  float mean = sum * (1.f / H_);
  float var = sq * (1.f / H_) - mean * mean;
  float rstd = rsqrtf(var + 1e-5f);
  u16x4 o = { f2bf((v0 - mean) * rstd), f2bf((v1 - mean) * rstd),
              f2bf((v2 - mean) * rstd), f2bf((v3 - mean) * rstd) };
  *(u16x4*)(xn + (size_t)row * H_ + tid * 4) = o;
}

// ---------------- QKV GEMM: 256x256 8-phase template (m201 port).
// BK=64, 8 waves (2Mx4N), per-wave 128x64, LDS 128KB = 2 slots x 2 halves x
// [128][64] row-XOR-swizzled bf16. Counted vmcnt(8) at phases 4/8 only.
__global__ __launch_bounds__(512) void qkv_kernel(
    const u16* __restrict__ xn, const u16* __restrict__ w16,
    const float* __restrict__ dc, u16* __restrict__ Qb, u16* __restrict__ Kb,
    u16* __restrict__ VT, u16* __restrict__ vfl) {
  __shared__ u16 lA[2][2][128 * 64];
  __shared__ u16 lB[2][2][128 * 64];
  int bid = blockIdx.x;                 // 384 = 48/XCD
  int swz = (bid & 7) * 48 + (bid >> 3);
  int bm = swz / 12, bn = swz % 12;
  const u16* A  = xn + (size_t)bm * 256 * H_;
  const u16* Bp = w16 + (size_t)bn * 256 * H_;
  int tid = threadIdx.x;
  int l = tid & 63, wid = tid >> 6;
  int wr = wid >> 2, wc = wid & 3;
  int lrow = l & 15, kc = l >> 4;
  // staging addresses: thread covers rows sr0, sr0+64 at chunk sch
  int sch = tid & 7, sr0 = tid >> 3;
  int slch = sch ^ (sr0 & 7);           // inverse-swizzled source chunk
  const size_t sSrc = (size_t)sr0 * H_ + slch * 8;
  const int sDst = sr0 * 64 + sch * 8;
#define STG(srcbase, dstarr) do { \
    gload16((srcbase) + sSrc, (dstarr) + sDst); \
    gload16((srcbase) + sSrc + (size_t)64 * H_, (dstarr) + sDst + 64 * 64); } while (0)
  // fragment-read chunk byte offsets (u16 units): chunk = (kk*4+kc)^(lrow&7)
  const int chk0 = ((kc) ^ (lrow & 7)) * 8;
  const int chk1 = ((4 + kc) ^ (lrow & 7)) * 8;
  const u16* Ah0 = lA[0][wr];
  const u16* Ah1 = lA[1][wr];
  const u16* Bh0 = lB[0][wc >> 1];
  const u16* Bh1 = lB[1][wc >> 1];
  const int brow = (wc & 1) * 64;
  // prologue: K-tiles 0 (slot0) and 1 (slot1); confirm kt0; barrier
  STG(Bp,                         lB[0][0]);
  STG(Bp + (size_t)128 * H_,      lB[0][1]);
  STG(A,                          lA[0][0]);
  STG(A + (size_t)128 * H_,       lA[0][1]);
  STG(Bp + 64,                    lB[1][0]);
  STG(Bp + (size_t)128 * H_ + 64, lB[1][1]);
  STG(A + 64,                     lA[1][0]);
  STG(A + (size_t)128 * H_ + 64,  lA[1][1]);
  asm volatile("s_waitcnt vmcnt(8)" ::: "memory");
  __builtin_amdgcn_s_barrier();
  f32x4 acc[8][4] = {};
  bf16x8 af[4][2], bfA[2][2], bfB[2][2];
#define PH_SYNC \
    __builtin_amdgcn_s_barrier(); \
    asm volatile("s_waitcnt lgkmcnt(0)" ::: "memory"); \
    __builtin_amdgcn_sched_barrier(0)
#define QMFMA(MO, NO, BF) \
    __builtin_amdgcn_s_setprio(1); \
    _Pragma("unroll") \
    for (int mi = 0; mi < 4; mi++) \
      _Pragma("unroll") \
      for (int ni = 0; ni < 2; ni++) { \
        acc[MO + mi][NO + ni] = MFMA(af[mi][0], BF[ni][0], acc[MO + mi][NO + ni]); \
        acc[MO + mi][NO + ni] = MFMA(af[mi][1], BF[ni][1], acc[MO + mi][NO + ni]); \
      } \
    __builtin_amdgcn_s_setprio(0)
  for (int i = 0; i < 8; ++i) {
    const int k2 = (2 * i + 2) * 64;
    const int k3 = (2 * i + 3) * 64;
    const bool more = (i < 7);
    // phase 1: read af(mh0) + bfA from slot0; MFMA Q00
#pragma unroll
    for (int mi = 0; mi < 4; mi++) {
      af[mi][0] = *(const bf16x8*)&Ah0[(mi * 16 + lrow) * 64 + chk0];
      af[mi][1] = *(const bf16x8*)&Ah0[(mi * 16 + lrow) * 64 + chk1];
    }
#pragma unroll
    for (int ni = 0; ni < 2; ni++) {
      bfA[ni][0] = *(const bf16x8*)&Bh0[(brow + ni * 16 + lrow) * 64 + chk0];
      bfA[ni][1] = *(const bf16x8*)&Bh0[(brow + ni * 16 + lrow) * 64 + chk1];
    }
    PH_SYNC;
    QMFMA(0, 0, bfA);
    __builtin_amdgcn_s_barrier();
    // phase 2: read bfB (slot0); MFMA Q01
#pragma unroll
    for (int ni = 0; ni < 2; ni++) {
      bfB[ni][0] = *(const bf16x8*)&Bh0[(brow + (2 + ni) * 16 + lrow) * 64 + chk0];
      bfB[ni][1] = *(const bf16x8*)&Bh0[(brow + (2 + ni) * 16 + lrow) * 64 + chk1];
    }
    PH_SYNC;
    QMFMA(0, 2, bfB);
    __builtin_amdgcn_s_barrier();
    // phase 3: read af(mh1, slot0); stage B slot0 <- kt+2; MFMA Q10
#pragma unroll
    for (int mi = 0; mi < 4; mi++) {
      af[mi][0] = *(const bf16x8*)&Ah0[((64 + mi * 16) + lrow) * 64 + chk0];
      af[mi][1] = *(const bf16x8*)&Ah0[((64 + mi * 16) + lrow) * 64 + chk1];
    }
    if (more) {
      STG(Bp + k2,                    lB[0][0]);
      STG(Bp + (size_t)128 * H_ + k2, lB[0][1]);
    }
    PH_SYNC;
    QMFMA(4, 0, bfA);
    __builtin_amdgcn_s_barrier();
    // phase 4: stage A slot0 <- kt+2; MFMA Q11; gate; barrier
    if (more) {
      STG(A + k2,                    lA[0][0]);
      STG(A + (size_t)128 * H_ + k2, lA[0][1]);
    }
    __builtin_amdgcn_s_barrier();
    QMFMA(4, 2, bfB);
    if (more) {
      asm volatile("s_waitcnt vmcnt(8)" ::: "memory");
    } else {
      asm volatile("s_waitcnt vmcnt(0)" ::: "memory");
    }
    __builtin_amdgcn_s_barrier();
    // phase 5: read af(mh0) + bfA from slot1; MFMA Q00
#pragma unroll
    for (int mi = 0; mi < 4; mi++) {
      af[mi][0] = *(const bf16x8*)&Ah1[(mi * 16 + lrow) * 64 + chk0];
      af[mi][1] = *(const bf16x8*)&Ah1[(mi * 16 + lrow) * 64 + chk1];
    }
#pragma unroll
    for (int ni = 0; ni < 2; ni++) {
      bfA[ni][0] = *(const bf16x8*)&Bh1[(brow + ni * 16 + lrow) * 64 + chk0];
      bfA[ni][1] = *(const bf16x8*)&Bh1[(brow + ni * 16 + lrow) * 64 + chk1];
    }
    PH_SYNC;
    QMFMA(0, 0, bfA);
    __builtin_amdgcn_s_barrier();
    // phase 6: read bfB (slot1); MFMA Q01
#pragma unroll
    for (int ni = 0; ni < 2; ni++) {
      bfB[ni][0] = *(const bf16x8*)&Bh1[(brow + (2 + ni) * 16 + lrow) * 64 + chk0];
      bfB[ni][1] = *(const bf16x8*)&Bh1[(brow + (2 + ni) * 16 + lrow) * 64 + chk1];
    }
    PH_SYNC;
    QMFMA(0, 2, bfB);
    __builtin_amdgcn_s_barrier();
    // phase 7: read af(mh1, slot1); stage B slot1 <- kt+3; MFMA Q10
#pragma unroll
    for (int mi = 0; mi < 4; mi++) {
      af[mi][0] = *(const bf16x8*)&Ah1[((64 + mi * 16) + lrow) * 64 + chk0];
      af[mi][1] = *(const bf16x8*)&Ah1[((64 + mi * 16) + lrow) * 64 + chk1];
    }
    if (more) {
      STG(Bp + k3,                    lB[1][0]);
      STG(Bp + (size_t)128 * H_ + k3, lB[1][1]);
    }
    PH_SYNC;
    QMFMA(4, 0, bfA);
    __builtin_amdgcn_s_barrier();
    // phase 8: stage A slot1 <- kt+3; MFMA Q11; gate; barrier
    if (more) {
      STG(A + k3,                    lA[1][0]);
      STG(A + (size_t)128 * H_ + k3, lA[1][1]);
    }
    __builtin_amdgcn_s_barrier();
    QMFMA(4, 2, bfB);
    if (more) {
      asm volatile("s_waitcnt vmcnt(8)" ::: "memory");
    }
    __builtin_amdgcn_s_barrier();
  }
#undef STG
#undef PH_SYNC
#undef QMFMA
  // epilogue
  int wsel = bn >> 2;
  int colm = (bn & 3) * 256 + wc * 64;
  int row0 = bm * 256 + wr * 128;
  const float* dcw = dc + (size_t)wsel * B_ * H_;
  float extra = (wsel == 0) ? 0.125f * L2E : 1.0f;
#pragma unroll
  for (int mi = 0; mi < 8; mi++) {
    int row = row0 + mi * 16 + (l >> 4) * 4;
    int b = row >> 10, s_base = row & 1023;
#pragma unroll
    for (int ni = 0; ni < 4; ni++) {
      int col = colm + ni * 16 + lrow;
      int hh = col >> 6, dd = col & 63;
      float dcv = dcw[b * H_ + col] * extra;
      u16 bv[4];
#pragma unroll
      for (int rr = 0; rr < 4; rr++)
        bv[rr] = f2bf(acc[mi][ni][rr] * dcv);
      if (wsel == 0) {
#pragma unroll
        for (int rr = 0; rr < 4; rr++)
          Qb[((size_t)(b * NH + hh) * S_ + s_base + rr) * DH + dd] = bv[rr];
      } else if (wsel == 1) {
#pragma unroll
        for (int rr = 0; rr < 4; rr++)
          Kb[((size_t)(b * NH + hh) * S_ + s_base + rr) * DH + dd] = bv[rr];
      } else {
        u16x4 pv = { bv[0], bv[1], bv[2], bv[3] };
        *(u16x4*)&VT[((size_t)(b * NH + hh) * DH + dd) * S_ + s_base] = pv;
#pragma unroll
        for (int rr = 0; rr < 4; rr++)
          vfl[(size_t)(row + rr) * H_ + col] = bv[rr];
      }
    }
  }
}

// ---------------- 128x128 NT GEMM core (m97-style, measured-best for out)
__device__ __forceinline__ void gemm128_core(
    const u16* __restrict__ Arow, const u16* __restrict__ Brow, int K,
    u16* ldsA, u16* ldsB, f32x4 acc[4][4]) {
  const int tid = threadIdx.x;
  const int l = tid & 63, w = tid >> 6;
  const int wm = (w >> 1) * 64, wn = (w & 1) * 64;
  const int lrow = l & 15, lko = (l >> 4) * 8;
  const int srow = tid >> 2;
  const int scol = (tid & 3) * 8;
  for (int k0 = 0; k0 < K; k0 += 32) {
    __syncthreads();
    gload16(Arow + (size_t)srow * K + k0 + scol,        ldsA + srow * 32 + scol);
    gload16(Arow + (size_t)(srow + 64) * K + k0 + scol, ldsA + (srow + 64) * 32 + scol);
    gload16(Brow + (size_t)srow * K + k0 + scol,        ldsB + srow * 32 + scol);
    gload16(Brow + (size_t)(srow + 64) * K + k0 + scol, ldsB + (srow + 64) * 32 + scol);
    __syncthreads();
    bf16x8 af[4], bfr[4];
#pragma unroll
    for (int i = 0; i < 4; i++)
      af[i] = *(const bf16x8*)&ldsA[(wm + i * 16 + lrow) * 32 + lko];
#pragma unroll
    for (int i = 0; i < 4; i++)
      bfr[i] = *(const bf16x8*)&ldsB[(wn + i * 16 + lrow) * 32 + lko];
#pragma unroll
    for (int mi = 0; mi < 4; mi++)
#pragma unroll
      for (int ni = 0; ni < 4; ni++)
        acc[mi][ni] = MFMA(af[mi], bfr[ni], acc[mi][ni]);
  }
}

// ---------------- flash attention (R8 version: 32 q-rows/wave, in-reg P)
__global__ __launch_bounds__(512) void attn_kernel(
    const u16* __restrict__ Qb, const u16* __restrict__ Kb,
    const u16* __restrict__ VT, u16* __restrict__ xat) {
  __shared__ u16 ldsK[3][64 * 64];
  __shared__ u16 ldsV[3][64 * 64];
  int tid = threadIdx.x;
  int l = tid & 63, w = tid >> 6;   // 8 waves, 32 q-rows each
  int id = blockIdx.x;
  int r = id & 7, rest = id >> 3;
  int qblk = rest & 3, a = rest >> 2;
  int hl = a * 8 + r;              // XCD-locality: same head -> same XCD
  int h = hl & 15, b = hl >> 4;
  int q0 = qblk * 256 + w * 32;
  const u16* Qp = Qb + ((size_t)(b * NH + h) * S_ + q0) * DH;
  const u16* Kp = Kb + (size_t)(b * NH + h) * S_ * DH;
  const u16* Vp = VT + (size_t)(b * NH + h) * DH * S_;
  int lq = l & 31, hi = l >> 5;
  int srow = tid >> 3, schunk = tid & 7;
  int ssw = (schunk * 8) ^ ((srow & 7) << 3);
  const u16* Ksrc = Kp + (size_t)srow * DH + ssw;
  const u16* Vsrc = Vp + (size_t)srow * S_ + ssw;
  int sdst = srow * 64 + schunk * 8;
  gload16(Ksrc, &ldsK[0][sdst]);
  gload16(Vsrc, &ldsV[0][sdst]);
  gload16(Ksrc + 64 * DH, &ldsK[1][sdst]);
  gload16(Vsrc + 64,      &ldsV[1][sdst]);
  bf16x8 qf[4];
#pragma unroll
  for (int s = 0; s < 4; s++)
    qf[s] = *(const bf16x8*)(Qp + lq * 64 + s * 16 + hi * 8);
  f32x16 acc0 = {}, acc1 = {};   // OUT^T d-blocks 0..31 / 32..63
  float ls = 0.f;
  asm volatile("s_waitcnt vmcnt(2)" ::: "memory");
  __builtin_amdgcn_s_barrier();
  int cur = 0;
  for (int t = 0; t < 16; ++t) {
    if (t + 2 < 16) {
      int nb = cur + 2; if (nb >= 3) nb -= 3;
      gload16(Ksrc + (size_t)(t + 2) * 64 * DH, &ldsK[nb][sdst]);
      gload16(Vsrc + (size_t)(t + 2) * 64,      &ldsV[nb][sdst]);
    }
    const u16* Kt = &ldsK[cur][0];
    const u16* Vt = &ldsV[cur][0];
    f32x16 z0 = {}, z1 = {};
    __builtin_amdgcn_s_setprio(1);
#pragma unroll
    for (int s = 0; s < 4; s++) {
      int ch = ((s * 2 + hi) ^ (lq & 7)) * 8;
      bf16x8 kf0 = *(const bf16x8*)&Kt[lq * 64 + ch];
      bf16x8 kf1 = *(const bf16x8*)&Kt[(32 + lq) * 64 + ch];
      z0 = MFMA32(kf0, qf[s], z0);
      z1 = MFMA32(kf1, qf[s], z1);
    }
    __builtin_amdgcn_s_setprio(0);
    float rs = 0.f;
#pragma unroll
    for (int i = 0; i < 16; i++) {
      z0[i] = __builtin_exp2f(z0[i]); rs += z0[i];
      z1[i] = __builtin_exp2f(z1[i]); rs += z1[i];
    }
    rs += __shfl_xor(rs, 32);
    ls += rs;
    bf16x8 pf[4];
#pragma unroll
    for (int g = 0; g < 2; g++) {
      unsigned pa = packbf2(z0[g * 8 + 0], z0[g * 8 + 1]);
      unsigned pb = packbf2(z0[g * 8 + 2], z0[g * 8 + 3]);
      unsigned pc = packbf2(z0[g * 8 + 4], z0[g * 8 + 5]);
      unsigned pd = packbf2(z0[g * 8 + 6], z0[g * 8 + 7]);
      u32x2 sA = __builtin_amdgcn_permlane32_swap(pa, pc, false, false);
      u32x2 sB = __builtin_amdgcn_permlane32_swap(pb, pd, false, false);
      union { unsigned u[4]; bf16x8 v; } uu;
      uu.u[0] = sA[0]; uu.u[1] = sB[0]; uu.u[2] = sA[1]; uu.u[3] = sB[1];
      pf[g] = uu.v;
    }
#pragma unroll
    for (int g = 0; g < 2; g++) {
      unsigned pa = packbf2(z1[g * 8 + 0], z1[g * 8 + 1]);
      unsigned pb = packbf2(z1[g * 8 + 2], z1[g * 8 + 3]);
      unsigned pc = packbf2(z1[g * 8 + 4], z1[g * 8 + 5]);
      unsigned pd = packbf2(z1[g * 8 + 6], z1[g * 8 + 7]);
      u32x2 sA = __builtin_amdgcn_permlane32_swap(pa, pc, false, false);
      u32x2 sB = __builtin_amdgcn_permlane32_swap(pb, pd, false, false);
      union { unsigned u[4]; bf16x8 v; } uu;
      uu.u[0] = sA[0]; uu.u[1] = sB[0]; uu.u[2] = sA[1]; uu.u[3] = sB[1];
      pf[2 + g] = uu.v;
    }
    __builtin_amdgcn_s_setprio(1);
#pragma unroll
    for (int ks = 0; ks < 4; ks++) {
      int ch = ((ks * 2 + hi) ^ (lq & 7)) * 8;
      bf16x8 vf0 = *(const bf16x8*)&Vt[lq * 64 + ch];
      bf16x8 vf1 = *(const bf16x8*)&Vt[(32 + lq) * 64 + ch];
      acc0 = MFMA32(vf0, pf[ks], acc0);
      acc1 = MFMA32(vf1, pf[ks], acc1);
    }
    __builtin_amdgcn_s_setprio(0);
    if (t < 14) {
      asm volatile("s_waitcnt vmcnt(2)" ::: "memory");
    } else if (t == 14) {
      asm volatile("s_waitcnt vmcnt(0)" ::: "memory");
    }
    if (t < 15) __builtin_amdgcn_s_barrier();
    cur = (cur == 2) ? 0 : cur + 1;
  }
  float inv = 1.f / ls;
  size_t orow = ((size_t)b * S_ + q0 + lq) * H_ + h * DH;
#pragma unroll
  for (int g = 0; g < 4; g++) {
    int d0 = g * 8 + hi * 4;
    u16x4 o0 = { f2bf(acc0[g * 4 + 0] * inv), f2bf(acc0[g * 4 + 1] * inv),
                 f2bf(acc0[g * 4 + 2] * inv), f2bf(acc0[g * 4 + 3] * inv) };
    *(u16x4*)(xat + orow + d0) = o0;
    u16x4 o1 = { f2bf(acc1[g * 4 + 0] * inv), f2bf(acc1[g * 4 + 1] * inv),
                 f2bf(acc1[g * 4 + 2] * inv), f2bf(acc1[g * 4 + 3] * inv) };
    *(u16x4*)(xat + orow + 32 + d0) = o1;
  }
}

// ---------------- out GEMM: (xat@W^T)*wdc + (vfl@U^T)*udc, f32 out
__global__ __launch_bounds__(256) void out_kernel(
    const u16* __restrict__ xat, const u16* __restrict__ vfl,
    const u16* __restrict__ w16, const float* __restrict__ dc,
    float* __restrict__ out) {
  __shared__ u16 ldsA[128 * 32], ldsB[128 * 32];
  int bm = blockIdx.x;   // 64
  int bn = blockIdx.y;   // 8
  f32x4 acc[4][4] = {};
  gemm128_core(xat + (size_t)bm * 128 * H_,
               w16 + (size_t)3 * H_ * H_ + (size_t)bn * 128 * H_, H_,
               ldsA, ldsB, acc);
  int l = threadIdx.x & 63, w = threadIdx.x >> 6;
  int wm = (w >> 1) * 64, wn = (w & 1) * 64;
  int col0 = bn * 128 + wn;
  int row0 = bm * 128 + wm;
  int b = row0 >> 10;
  const float* wdc = dc + (size_t)3 * B_ * H_ + b * H_;
  const float* udc = dc + (size_t)4 * B_ * H_ + b * H_;
  float ratio[4], ud[4];
#pragma unroll
  for (int ni = 0; ni < 4; ni++) {
    int col = col0 + ni * 16 + (l & 15);
    ud[ni] = udc[col];
    ratio[ni] = wdc[col] / ud[ni];
  }
#pragma unroll
  for (int mi = 0; mi < 4; mi++)
#pragma unroll
    for (int ni = 0; ni < 4; ni++)
#pragma unroll
      for (int rr = 0; rr < 4; rr++) acc[mi][ni][rr] *= ratio[ni];
  gemm128_core(vfl + (size_t)bm * 128 * H_,
               w16 + (size_t)4 * H_ * H_ + (size_t)bn * 128 * H_, H_,
               ldsA, ldsB, acc);
#pragma unroll
  for (int mi = 0; mi < 4; mi++)
#pragma unroll
    for (int ni = 0; ni < 4; ni++) {
      int col = col0 + ni * 16 + (l & 15);
#pragma unroll
      for (int rr = 0; rr < 4; rr++) {
        int row = row0 + mi * 16 + (l >> 4) * 4 + rr;
        out[(size_t)row * H_ + col] = acc[mi][ni][rr] * ud[ni];
      }
    }
}

extern "C" void kernel_launch(void* const* d_in, const int* in_sizes, int n_in,
                              void* d_out, int out_size, void* d_ws, size_t ws_size,
                              hipStream_t stream) {
  const float* x = (const float*)d_in[0];
  const float* qw = (const float*)d_in[1];
  const float* kw = (const float*)d_in[2];
  const float* vw = (const float*)d_in[3];
  const float* ww = (const float*)d_in[4];
  const float* uw = (const float*)d_in[5];
  const float* styles = (const float*)d_in[6];
  float* out = (float*)d_out;

  char* ws = (char*)d_ws;
  size_t need = 163840 + (size_t)5 * H_ * H_ * 2 + (size_t)6 * BS * H_ * 2;
  if (ws_size < need) return;
  float* dc = (float*)ws;
  u16* w16 = (u16*)(ws + 163840);
  u16* xn  = w16 + (size_t)5 * H_ * H_;
  u16* Qb  = xn + (size_t)BS * H_;
  u16* Kb  = Qb + (size_t)BS * H_;
  u16* VT  = Kb + (size_t)BS * H_;
  u16* vfl = VT + (size_t)BS * H_;
  u16* xat = vfl + (size_t)BS * H_;

  dcoef_kernel<<<dim3(5 * H_), dim3(256), 0, stream>>>(qw, kw, vw, ww, uw, styles, dc, w16);
  ln_kernel<<<dim3(BS), dim3(256), 0, stream>>>(x, styles, xn);
  qkv_kernel<<<dim3(384), dim3(512), 0, stream>>>(xn, w16, dc, Qb, Kb, VT, vfl);
  attn_kernel<<<dim3(512), dim3(512), 0, stream>>>(Qb, Kb, VT, xat);
  out_kernel<<<dim3(64, 8), dim3(256), 0, stream>>>(xat, vfl, w16, dc, out);
}